// Round 15
// baseline (36636.987 us; speedup 1.0000x reference)
//
#include <hip/hip_runtime.h>
#include <stdint.h>

#define NTHR 256
#define NBLKS 256

namespace cfg {
// ws layout in FLOAT units (R13 layout)
constexpr size_t F_CELLS = 0;                     // arr[512] u32 + rel[512*32] u32
constexpr size_t F_H0    = 524288;                // [32][512]
constexpr size_t F_C0    = F_H0 + 16384;
constexpr size_t F_H1    = F_C0 + 16384;
constexpr size_t F_C1    = F_H1 + 16384;
constexpr size_t F_ATTNS = F_C1 + 16384;          // [2][32][512] attn vector (parity dbuf)
constexpr size_t F_VN    = F_ATTNS + 32768;       // [512]
constexpr size_t F_CTX   = F_VN + 512;            // [32][1024]
constexpr size_t F_AALL  = F_CTX + 32768;         // [128][32][512] attn history
constexpr size_t F_EOUT  = F_AALL + 2097152;      // [32][128][1024] (write-once)
constexpr size_t F_KEYS  = F_EOUT + 4194304;      // [32][128][512]  (write-once)
constexpr size_t F_TOTAL = F_KEYS + 2097152;      // ~36.2 MB (proven budget)
constexpr size_t MEMSET_BYTES = F_VN * 4;         // cells + states + attn_s
// gate-partial scratch in the OUT buffer (dead until final projection):
constexpr size_t O_P0 = 0;        // [12][32][2048] (dec A; enc fw uses 8)
constexpr size_t O_P1 = 786432;   // [16][32][2048] (dec C; enc bw uses 8)
}

__device__ __forceinline__ float sigm(float x)   { return 1.0f / (1.0f + __expf(-x)); }
__device__ __forceinline__ float tanhft(float x) { return 1.0f - 2.0f / (1.0f + __expf(2.0f * x)); }

// 32-bit agent-scope access — the ONLY uncached primitive (proven)
__device__ __forceinline__ float cload(const float* p) {
  return __hip_atomic_load(p, __ATOMIC_RELAXED, __HIP_MEMORY_SCOPE_AGENT);
}
__device__ __forceinline__ void cstore(float* p, float v) {
  __hip_atomic_store(p, v, __ATOMIC_RELAXED, __HIP_MEMORY_SCOPE_AGENT);
}

// checker/broadcast grid barrier, 256 blocks (R4-proven mechanism)
__device__ __forceinline__ void gbar(unsigned ep, unsigned* arr, unsigned* rel) {
  __syncthreads();
  if (blockIdx.x == 0) {
    if (threadIdx.x == 0)
      __hip_atomic_store(arr, ep, __ATOMIC_RELAXED, __HIP_MEMORY_SCOPE_AGENT);
    while (__hip_atomic_load(arr + threadIdx.x, __ATOMIC_RELAXED, __HIP_MEMORY_SCOPE_AGENT) < ep)
      __builtin_amdgcn_s_sleep(1);
    __syncthreads();
    __hip_atomic_store(rel + (size_t)threadIdx.x * 32, ep, __ATOMIC_RELAXED, __HIP_MEMORY_SCOPE_AGENT);
    __syncthreads();
  } else {
    if (threadIdx.x == 0) {
      __hip_atomic_store(arr + blockIdx.x, ep, __ATOMIC_RELAXED, __HIP_MEMORY_SCOPE_AGENT);
      while (__hip_atomic_load(rel + (size_t)blockIdx.x * 32, __ATOMIC_RELAXED,
                               __HIP_MEMORY_SCOPE_AGENT) < ep)
        __builtin_amdgcn_s_sleep(1);
    }
    __syncthreads();
  }
}

// stage A-tile [32][KWIN] into LDS — gather into regs, then write (R9-proven)
template<int KWIN, typename F>
__device__ __forceinline__ void stage(float* at, F&& f) {
  static_assert((32 * KWIN) % NTHR == 0, "tile must tile NTHR");
  constexpr int PER = (32 * KWIN) / NTHR;
  __syncthreads();
  float v[PER];
#pragma unroll
  for (int r = 0; r < PER; r++) {
    int i = threadIdx.x + NTHR * r;
    v[r] = f(i / KWIN, i % KWIN);
  }
#pragma unroll
  for (int r = 0; r < PER; r++) at[threadIdx.x + NTHR * r] = v[r];
  __syncthreads();
}

// single-column GEMM fragment (R10-proven): preload KQ weight rows, then FMA
template<int KWIN>
__device__ __forceinline__ void gemm_frag(const float* __restrict__ W, int ldw,
                                          int n, bool nok, int kw0,
                                          const float* at, float* acc) {
  const int wave = threadIdx.x >> 6;
  constexpr int KQ = KWIN / 4;
  const int klo = wave * KQ;
  const float* wp = W + (size_t)(kw0 + klo) * (size_t)ldw + n;
  float w[KQ];
#pragma unroll
  for (int j = 0; j < KQ; j++) w[j] = nok ? wp[(size_t)j * ldw] : 0.f;
#pragma unroll
  for (int jj = 0; jj < KQ; jj += 4) {
    const float* ap = at + klo + jj;
#pragma unroll
    for (int m = 0; m < 32; m++) {
      float4 a = *(const float4*)(ap + m * KWIN);
      acc[m] = fmaf(a.x, w[jj + 0], acc[m]);
      acc[m] = fmaf(a.y, w[jj + 1], acc[m]);
      acc[m] = fmaf(a.z, w[jj + 2], acc[m]);
      acc[m] = fmaf(a.w, w[jj + 3], acc[m]);
    }
  }
}

// dual-column GEMM: two column groups share one staged tile. Weight loads for
// both columns issued back-to-back per KQSUB sub-batch (one latency round).
template<int KWIN, int KQSUB>
__device__ __forceinline__ void gemm_frag2(const float* __restrict__ W, int ldw,
                                           int n1, int n2, int kw0,
                                           const float* at, float* accA, float* accB) {
  const int wave = threadIdx.x >> 6;
  constexpr int KQ = KWIN / 4;
  static_assert(KQ % KQSUB == 0 && KQSUB % 4 == 0, "bad KQSUB");
  const int klo = wave * KQ;
#pragma unroll 1
  for (int kk0 = 0; kk0 < KQ; kk0 += KQSUB) {
    const float* wpA = W + (size_t)(kw0 + klo + kk0) * (size_t)ldw + n1;
    const float* wpB = W + (size_t)(kw0 + klo + kk0) * (size_t)ldw + n2;
    float wA[KQSUB], wB[KQSUB];
#pragma unroll
    for (int j = 0; j < KQSUB; j++) wA[j] = wpA[(size_t)j * ldw];
#pragma unroll
    for (int j = 0; j < KQSUB; j++) wB[j] = wpB[(size_t)j * ldw];
#pragma unroll
    for (int jj = 0; jj < KQSUB; jj += 4) {
      const float* ap = at + klo + kk0 + jj;
#pragma unroll
      for (int m = 0; m < 32; m++) {
        float4 a = *(const float4*)(ap + m * KWIN);
        accA[m] = fmaf(a.x, wA[jj + 0], accA[m]);
        accA[m] = fmaf(a.y, wA[jj + 1], accA[m]);
        accA[m] = fmaf(a.z, wA[jj + 2], accA[m]);
        accA[m] = fmaf(a.w, wA[jj + 3], accA[m]);
        accB[m] = fmaf(a.x, wB[jj + 0], accB[m]);
        accB[m] = fmaf(a.y, wB[jj + 1], accB[m]);
        accB[m] = fmaf(a.z, wB[jj + 2], accB[m]);
        accB[m] = fmaf(a.w, wB[jj + 3], accB[m]);
      }
    }
  }
}

// red layout [4][32][64] = 8192 floats (proven)
__device__ __forceinline__ void red_write(float* red, const float* acc) {
  const int wave = threadIdx.x >> 6, lane = threadIdx.x & 63;
  __syncthreads();
#pragma unroll
  for (int m = 0; m < 32; m++) red[(wave * 32 + m) * 64 + lane] = acc[m];
  __syncthreads();
}
__device__ __forceinline__ float redsum(const float* red, int m, int c) {
  return red[m * 64 + c] + red[2048 + m * 64 + c] +
         red[4096 + m * 64 + c] + red[6144 + m * 64 + c];
}

__device__ __forceinline__ void epi_cstore(const float* red, float* outp, int ldo, int n0) {
  for (int i = threadIdx.x; i < 2048; i += NTHR) {
    int m = i >> 6, nn = i & 63;
    cstore(outp + (size_t)m * ldo + n0 + nn, redsum(red, m, nn));
  }
}

// ALL 4 gates x NKB partial loads issued back-to-back, then sum (R10-proven)
template<int NKB>
__device__ __forceinline__ void gate_sum4(const float* base, float g4[4]) {
  float v[4][NKB];
#pragma unroll
  for (int g = 0; g < 4; g++) {
    const float* p = base + g * 512;
#pragma unroll
    for (int j = 0; j < NKB; j++) v[g][j] = cload(p + (size_t)j * 65536);
  }
#pragma unroll
  for (int g = 0; g < 4; g++) {
    float s = 0.f;
#pragma unroll
    for (int j = 0; j < NKB; j++) s += v[g][j];
    g4[g] = s;
  }
}

__global__ __launch_bounds__(NTHR, 1) void seq2seq_kernel(
    const float* __restrict__ embed_in, const float* __restrict__ dec_embed,
    const int* __restrict__ lens,
    const float* __restrict__ Wfw, const float* __restrict__ bfw,
    const float* __restrict__ Wbw, const float* __restrict__ bbw,
    const float* __restrict__ Wd0, const float* __restrict__ bd0,
    const float* __restrict__ Wd1, const float* __restrict__ bd1,
    const float* __restrict__ Wmem, const float* __restrict__ Wq,
    const float* __restrict__ battn, const float* __restrict__ vattn,
    const float* __restrict__ gattn, const float* __restrict__ Wal,
    const float* __restrict__ Wproj, const float* __restrict__ bproj,
    float* __restrict__ out, float* ws) {
  __shared__ float smem[12288];  // 48 KiB: at=[0,4096), red=[4096,12288)
  float* at  = smem;
  float* red = smem + 4096;

  unsigned* arr = (unsigned*)ws;        // [256]
  unsigned* rel = (unsigned*)ws + 512;  // [256*32]
  float* h0     = ws + cfg::F_H0;
  float* c0     = ws + cfg::F_C0;
  float* h1     = ws + cfg::F_H1;
  float* c1     = ws + cfg::F_C1;
  float* attn_s = ws + cfg::F_ATTNS;  // parity stride 16384
  float* vn     = ws + cfg::F_VN;
  float* ctx    = ws + cfg::F_CTX;
  float* aall   = ws + cfg::F_AALL;   // [128][32][512]
  float* eout   = ws + cfg::F_EOUT;
  float* keysp  = ws + cfg::F_KEYS;
  float* p0     = out + cfg::O_P0;    // gate-partial scratch in OUT buffer
  float* p1     = out + cfg::O_P1;    // (dead by the time projection writes)

  const int bid = blockIdx.x, tid = threadIdx.x;
  const int wave = tid >> 6, lane = tid & 63;
  unsigned ep = 1;
#define BAR()  do { gbar(ep, arr, rel); ep++; } while (0)
#define BARSEAL() do { __threadfence(); gbar(ep, arr, rel); ep++; __threadfence(); } while (0)

  // ---------------- setup: normalized attention vector ----------------
  if (bid == 0) {
    float s = 0.f;
    for (int u = tid; u < 512; u += NTHR) { float x = vattn[u]; s = fmaf(x, x, s); }
#pragma unroll
    for (int off = 32; off > 0; off >>= 1) s += __shfl_xor(s, off, 64);
    if (lane == 0) at[64 + wave] = s;
    __syncthreads();
    float S = at[64] + at[65] + at[66] + at[67];
    float scale = gattn[0] / sqrtf(S);
    for (int u = tid; u < 512; u += NTHR) vn[u] = vattn[u] * scale;  // plain; sealed below
  }
  BAR();

  // ---------------- bidirectional encoder ----------------
  for (int t = 0; t < 128; t++) {
    // phase A: gate GEMMs, 256 blocks: dir(2) x kb(8) x nbp(16), KWIN=128,
    // each block covers nb = nbp and nbp+16 (two column groups, one staged tile)
    {
      int dir = bid >> 7;
      int r = bid & 127;
      int kb = r >> 4, nbp = r & 15;
      const float* W = dir ? Wbw : Wfw;
      const float* hs = dir ? h1 : h0;
      stage<128>(at, [&](int m, int kl) -> float {
        int kk = kb * 128 + kl;
        if (kk < 512) {
          int tt = t;
          if (dir) { int len = lens[m]; tt = (t < len) ? (len - 1 - t) : t; }
          return embed_in[((size_t)m * 128 + tt) * 512 + kk];  // read-only cached
        }
        return cload(hs + m * 512 + kk - 512);
      });
      float accA[32], accB[32];
#pragma unroll
      for (int m = 0; m < 32; m++) { accA[m] = 0.f; accB[m] = 0.f; }
      gemm_frag2<128, 16>(W, 2048, nbp * 64 + lane, (nbp + 16) * 64 + lane,
                          kb * 128, at, accA, accB);
      float* dst = (dir ? p1 : p0) + (size_t)kb * 65536;
      red_write(red, accA);
      epi_cstore(red, dst, 2048, nbp * 64);
      red_write(red, accB);
      epi_cstore(red, dst, 2048, (nbp + 16) * 64);
    }
    BAR();
    // phase B: activations + masked state update + enc_out write (128 blocks)
    if (bid < 128) {
      int dir = bid >> 6;
      int p = (bid & 63) * NTHR + tid;  // 0..16383
      int m = p >> 9, u = p & 511;
      const float* parts = dir ? p1 : p0;
      const float* bias  = dir ? bbw : bfw;
      float* hs = dir ? h1 : h0;
      float* cs = dir ? c1 : c0;
      float g4[4];
      gate_sum4<8>(parts + m * 2048 + u, g4);
#pragma unroll
      for (int g = 0; g < 4; g++) g4[g] += bias[g * 512 + u];
      int len = lens[m];
      bool valid = t < len;
      float co = cload(cs + m * 512 + u);
      float cn = sigm(g4[2] + 1.f) * co + sigm(g4[0]) * tanhft(g4[1]);
      float hn = sigm(g4[3]) * tanhft(cn);
      if (valid) { cstore(cs + m * 512 + u, cn); cstore(hs + m * 512 + u, hn); }
      int tpos = dir ? (valid ? (len - 1 - t) : t) : t;
      eout[((size_t)m * 128 + tpos) * 1024 + dir * 512 + u] = valid ? hn : 0.f;  // sealed
    }
    BAR();
  }

  BARSEAL();  // seal eout + vn

  // ---------------- keys = enc_out @ w_mem (1024 tasks over 256 blocks) ----------------
  {
#pragma unroll 1
    for (int task = bid; task < 1024; task += NBLKS) {
      int mt = task >> 3, nb = task & 7;
      int n0 = nb * 64;
      const float* arow = eout + (size_t)mt * 32 * 1024;
      float acc[32];
#pragma unroll
      for (int m = 0; m < 32; m++) acc[m] = 0.f;
      const int n = n0 + lane;
#pragma unroll 1
      for (int c = 0; c < 8; c++) {
        stage<128>(at, [&](int m, int kl) -> float {
          return arow[(size_t)m * 1024 + c * 128 + kl];
        });
        gemm_frag<128>(Wmem, 512, n, true, c * 128, at, acc);
      }
      red_write(red, acc);
      for (int i = tid; i < 2048; i += NTHR) {
        int m = i >> 6, nn = i & 63;
        keysp[(size_t)mt * 32 * 512 + (size_t)m * 512 + n0 + nn] = redsum(red, m, nn);
      }
    }
  }
  BARSEAL();  // seal keys

  // ---------------- decoder loop (5 phases/step; projection deferred) ----------------
  for (int t = 0; t < 128; t++) {
    // phase A: gates0 GEMM, K=1536; 192 blocks: kb(12) x nbp(16), KWIN=128, dual-col
    //          || blocks 192..199: copy attn(t-1) -> aall[t-1]
    if (bid < 192) {
      int kb = bid >> 4, nbp = bid & 15;  // kb 0..11
      const float* asrc = attn_s + (size_t)((t + 1) & 1) * 16384;  // attn(t-1)
      stage<128>(at, [&](int m, int kl) -> float {
        int kk = kb * 128 + kl;
        if (kk < 512) return dec_embed[((size_t)m * 128 + t) * 512 + kk];
        if (kk < 1024) return cload(asrc + m * 512 + kk - 512);
        return cload(h0 + m * 512 + kk - 1024);
      });
      float accA[32], accB[32];
#pragma unroll
      for (int m = 0; m < 32; m++) { accA[m] = 0.f; accB[m] = 0.f; }
      gemm_frag2<128, 16>(Wd0, 2048, nbp * 64 + lane, (nbp + 16) * 64 + lane,
                          kb * 128, at, accA, accB);
      float* dst = p0 + (size_t)kb * 65536;
      red_write(red, accA);
      epi_cstore(red, dst, 2048, nbp * 64);
      red_write(red, accB);
      epi_cstore(red, dst, 2048, (nbp + 16) * 64);
    } else if (bid < 200 && t >= 1) {
      const float* asrc = attn_s + (size_t)((t + 1) & 1) * 16384;  // attn(t-1)
      float v[8];
      int j8 = ((bid - 192) * 256 + tid) * 8;
#pragma unroll
      for (int k = 0; k < 8; k++) v[k] = cload(asrc + j8 + k);
#pragma unroll
      for (int k = 0; k < 8; k++) aall[(size_t)(t - 1) * 16384 + j8 + k] = v[k];
    }
    BAR();

    // phase B: act0 (blocks 0..63) + zero attn_s[t&1] (64..71)
    if (bid < 64) {
      int p = bid * NTHR + tid;
      int m = p >> 9, u = p & 511;
      float g4[4];
      gate_sum4<12>(p0 + m * 2048 + u, g4);
#pragma unroll
      for (int g = 0; g < 4; g++) g4[g] += bd0[g * 512 + u];
      float co = cload(c0 + m * 512 + u);
      float cn = sigm(g4[2] + 1.f) * co + sigm(g4[0]) * tanhft(g4[1]);
      float hn = sigm(g4[3]) * tanhft(cn);
      cstore(c0 + m * 512 + u, cn);
      cstore(h0 + m * 512 + u, hn);
    } else if (bid < 72) {
      float* az = attn_s + (size_t)(t & 1) * 16384 + (size_t)(bid - 64) * 2048;
      for (int i = tid; i < 2048; i += NTHR) cstore(az + i, 0.f);
    }
    BAR();

    // phase C: gates1 GEMM, K=1024; 256 blocks: kb(16) x nbp(16), KWIN=64, dual-col
    {
      int kb = bid >> 4, nbp = bid & 15;  // kb 0..15
      stage<64>(at, [&](int m, int kl) -> float {
        int kk = kb * 64 + kl;
        return (kk < 512) ? cload(h0 + m * 512 + kk) : cload(h1 + m * 512 + kk - 512);
      });
      float accA[32], accB[32];
#pragma unroll
      for (int m = 0; m < 32; m++) { accA[m] = 0.f; accB[m] = 0.f; }
      gemm_frag2<64, 16>(Wd1, 2048, nbp * 64 + lane, (nbp + 16) * 64 + lane,
                         kb * 64, at, accA, accB);
      float* dst = p1 + (size_t)kb * 65536;
      red_write(red, accA);
      epi_cstore(red, dst, 2048, nbp * 64);
      red_write(red, accB);
      epi_cstore(red, dst, 2048, (nbp + 16) * 64);
    }
    BAR();

    // phase E: attention, one block per batch row (blocks 0..31)
    if (bid < 32) {
      int b = bid;
      int len = lens[b];
      float* sh_h1v = at;          // 512
      float* sh_qb  = at + 512;    // 512
      float* sh_vnv = at + 1024;   // 512
      float* sh_sc  = at + 1536;   // 128
      float* sh_al  = at + 1664;   // 128
      float* sh_r   = at + 1792;   // 16
      float* redq   = at + 2048;   // 2048 (ends at at[4096))
      // act1 for row b (sole writer; batched partial loads)
#pragma unroll 1
      for (int u = tid; u < 512; u += NTHR) {
        float g4[4];
        gate_sum4<16>(p1 + b * 2048 + u, g4);
#pragma unroll
        for (int g = 0; g < 4; g++) g4[g] += bd1[g * 512 + u];
        float co = cload(c1 + b * 512 + u);
        float cn = sigm(g4[2] + 1.f) * co + sigm(g4[0]) * tanhft(g4[1]);
        float hn = sigm(g4[3]) * tanhft(cn);
        cstore(c1 + b * 512 + u, cn);
        cstore(h1 + b * 512 + u, hn);
        sh_h1v[u] = hn;
        sh_vnv[u] = vn[u];
      }
      __syncthreads();
      // q = h1n @ w_query — batched x8
      {
        float4 qa = make_float4(0.f, 0.f, 0.f, 0.f), qb4 = make_float4(0.f, 0.f, 0.f, 0.f);
        const int ua = lane * 4, ub = 256 + lane * 4;
        const float* wqp = Wq + (size_t)(wave * 128) * 512;
#pragma unroll 1
        for (int kk = 0; kk < 128; kk += 8) {
          float4 wa[8], wb[8];
#pragma unroll
          for (int j = 0; j < 8; j++) {
            wa[j] = *(const float4*)(wqp + (size_t)(kk + j) * 512 + ua);
            wb[j] = *(const float4*)(wqp + (size_t)(kk + j) * 512 + ub);
          }
#pragma unroll
          for (int j = 0; j < 8; j++) {
            float h = sh_h1v[wave * 128 + kk + j];
            qa.x = fmaf(h, wa[j].x, qa.x); qa.y = fmaf(h, wa[j].y, qa.y);
            qa.z = fmaf(h, wa[j].z, qa.z); qa.w = fmaf(h, wa[j].w, qa.w);
            qb4.x = fmaf(h, wb[j].x, qb4.x); qb4.y = fmaf(h, wb[j].y, qb4.y);
            qb4.z = fmaf(h, wb[j].z, qb4.z); qb4.w = fmaf(h, wb[j].w, qb4.w);
          }
        }
        *(float4*)(redq + wave * 512 + ua) = qa;
        *(float4*)(redq + wave * 512 + ub) = qb4;
      }
      __syncthreads();
      for (int u = tid; u < 512; u += NTHR)
        sh_qb[u] = redq[u] + redq[512 + u] + redq[1024 + u] + redq[1536 + u] + battn[u];
      __syncthreads();
      // scores — batched x4
#pragma unroll 1
      for (int tt = 0; tt < 32; tt += 4) {
        float4 kv[4][2];
#pragma unroll
        for (int j = 0; j < 4; j++) {
          const float* kp = keysp + ((size_t)b * 128 + wave * 32 + tt + j) * 512;
          kv[j][0] = *(const float4*)(kp + lane * 4);
          kv[j][1] = *(const float4*)(kp + lane * 4 + 256);
        }
#pragma unroll
        for (int j = 0; j < 4; j++) {
          int tq = wave * 32 + tt + j;
          float s = 0.f;
#pragma unroll
          for (int hh = 0; hh < 2; hh++) {
            int u = lane * 4 + hh * 256;
            float4 k4 = kv[j][hh];
            s += sh_vnv[u + 0] * tanhft(k4.x + sh_qb[u + 0]);
            s += sh_vnv[u + 1] * tanhft(k4.y + sh_qb[u + 1]);
            s += sh_vnv[u + 2] * tanhft(k4.z + sh_qb[u + 2]);
            s += sh_vnv[u + 3] * tanhft(k4.w + sh_qb[u + 3]);
          }
#pragma unroll
          for (int off = 32; off > 0; off >>= 1) s += __shfl_xor(s, off, 64);
          if (lane == 0) sh_sc[tq] = (tq < len) ? s : -1e30f;
        }
      }
      __syncthreads();
      // softmax over 128
      {
        float v = (tid < 128) ? sh_sc[tid] : -1e30f;
        float mx = v;
#pragma unroll
        for (int off = 32; off > 0; off >>= 1) mx = fmaxf(mx, __shfl_xor(mx, off, 64));
        if (lane == 0) sh_r[wave] = mx;
        __syncthreads();
        mx = fmaxf(fmaxf(sh_r[0], sh_r[1]), fmaxf(sh_r[2], sh_r[3]));
        float e = (tid < 128 && tid < len) ? __expf(v - mx) : 0.f;
        float sum = e;
#pragma unroll
        for (int off = 32; off > 0; off >>= 1) sum += __shfl_xor(sum, off, 64);
        if (lane == 0) sh_r[8 + wave] = sum;
        __syncthreads();
        float inv = 1.f / (sh_r[8] + sh_r[9] + sh_r[10] + sh_r[11]);
        if (tid < 128) sh_al[tid] = e * inv;   // 0 for masked entries
      }
      __syncthreads();
      // context = alpha @ enc_out[b] — batched x8; masked rows have alpha=0
      {
        int d = tid * 4;
        float4 acc = make_float4(0.f, 0.f, 0.f, 0.f);
        const float* ep2 = eout + (size_t)b * 128 * 1024 + d;
#pragma unroll 1
        for (int tq0 = 0; tq0 < 128; tq0 += 8) {
          float4 e4[8];
#pragma unroll
          for (int j = 0; j < 8; j++)
            e4[j] = *(const float4*)(ep2 + (size_t)(tq0 + j) * 1024);
#pragma unroll
          for (int j = 0; j < 8; j++) {
            float a = sh_al[tq0 + j];
            acc.x = fmaf(a, e4[j].x, acc.x); acc.y = fmaf(a, e4[j].y, acc.y);
            acc.z = fmaf(a, e4[j].z, acc.z); acc.w = fmaf(a, e4[j].w, acc.w);
          }
        }
        cstore(ctx + b * 1024 + d + 0, acc.x);
        cstore(ctx + b * 1024 + d + 1, acc.y);
        cstore(ctx + b * 1024 + d + 2, acc.z);
        cstore(ctx + b * 1024 + d + 3, acc.w);
      }
    }
    BAR();

    // phase F: attn(t) = (h1|ctx) @ Wal; 64 blocks: kb(16) x nbp(4), KWIN=96, dual-col
    if (bid < 64) {
      int kb = bid >> 2, nbp = bid & 3;  // kb 0..15, nbp 0..3 (cols nbp and nbp+4)
      stage<96>(at, [&](int m, int kl) -> float {
        int kk = kb * 96 + kl;
        return (kk < 512) ? cload(h1 + m * 512 + kk) : cload(ctx + m * 1024 + kk - 512);
      });
      float accA[32], accB[32];
#pragma unroll
      for (int m = 0; m < 32; m++) { accA[m] = 0.f; accB[m] = 0.f; }
      gemm_frag2<96, 24>(Wal, 512, nbp * 64 + lane, (nbp + 4) * 64 + lane,
                         kb * 96, at, accA, accB);
      float* adst = attn_s + (size_t)(t & 1) * 16384;
      red_write(red, accA);
      for (int i = tid; i < 2048; i += NTHR) {
        int m = i >> 6, nn = i & 63;
        atomicAdd(adst + (size_t)m * 512 + nbp * 64 + nn, redsum(red, m, nn));
      }
      red_write(red, accB);
      for (int i = tid; i < 2048; i += NTHR) {
        int m = i >> 6, nn = i & 63;
        atomicAdd(adst + (size_t)m * 512 + (nbp + 4) * 64 + nn, redsum(red, m, nn));
      }
    }
    BAR();
  }

  // trailing copy: attn(127) -> aall[127]  (parity slot 127&1 = 1)
  if (bid >= 192 && bid < 200) {
    const float* asrc = attn_s + (size_t)1 * 16384;
    float v[8];
    int j8 = ((bid - 192) * 256 + tid) * 8;
#pragma unroll
    for (int k = 0; k < 8; k++) v[k] = cload(asrc + j8 + k);
#pragma unroll
    for (int k = 0; k < 8; k++) aall[(size_t)127 * 16384 + j8 + k] = v[k];
  }
  BARSEAL();  // seal aall for cached readers; p0/p1 scratch now dead

  // ---------------- batched projection: out = aall @ Wproj + bproj ----------------
#pragma unroll 1
  for (int task = bid; task < 564; task += NBLKS) {
    int nb = task >> 2, tq = task & 3;  // nb 0..140, tq 0..3
    int n0 = nb * 64;
    const int col = n0 + lane;
    const bool ok = col < 9000;
#pragma unroll 1
    for (int t = tq * 32; t < tq * 32 + 32; t++) {
      const float* asrc = aall + (size_t)t * 16384;
      float acc[32];
#pragma unroll
      for (int m = 0; m < 32; m++) acc[m] = 0.f;
#pragma unroll 1
      for (int c = 0; c < 4; c++) {
        stage<128>(at, [&](int m, int kl) -> float {
          return asrc[(size_t)m * 512 + c * 128 + kl];  // plain cached (sealed)
        });
        gemm_frag<128>(Wproj, 9000, col, ok, c * 128, at, acc);
      }
      red_write(red, acc);
      for (int i = tid; i < 2048; i += NTHR) {
        int m = i >> 6, nn = i & 63;
        int nc = n0 + nn;
        if (nc < 9000)
          out[((size_t)m * 128 + t) * 9000 + nc] = redsum(red, m, nn) + bproj[nc];
      }
    }
  }
#undef BAR
#undef BARSEAL
}

extern "C" void kernel_launch(void* const* d_in, const int* in_sizes, int n_in,
                              void* d_out, int out_size, void* d_ws, size_t ws_size,
                              hipStream_t stream) {
  (void)in_sizes; (void)n_in; (void)out_size; (void)ws_size;
  hipMemsetAsync(d_ws, 0, cfg::MEMSET_BYTES, stream);  // cells + states + attn_s
  hipLaunchKernelGGL(seq2seq_kernel, dim3(NBLKS), dim3(NTHR), 0, stream,
                     (const float*)d_in[0],   // embed_in
                     (const float*)d_in[1],   // dec_embed
                     (const int*)d_in[2],     // in_seq_len
                     (const float*)d_in[3],   // enc_fw_kernel
                     (const float*)d_in[4],   // enc_fw_bias
                     (const float*)d_in[5],   // enc_bw_kernel
                     (const float*)d_in[6],   // enc_bw_bias
                     (const float*)d_in[7],   // dec_kernel0
                     (const float*)d_in[8],   // dec_bias0
                     (const float*)d_in[9],   // dec_kernel1
                     (const float*)d_in[10],  // dec_bias1
                     (const float*)d_in[11],  // w_mem
                     (const float*)d_in[12],  // w_query
                     (const float*)d_in[13],  // b_attn
                     (const float*)d_in[14],  // v_attn
                     (const float*)d_in[15],  // g_attn
                     (const float*)d_in[16],  // w_attn_layer
                     (const float*)d_in[17],  // w_proj
                     (const float*)d_in[18],  // b_proj
                     (float*)d_out, (float*)d_ws);
}

// Round 16
// 18393.040 us; speedup vs baseline: 1.9919x; 1.9919x over previous
//
#include <hip/hip_runtime.h>
#include <stdint.h>

#define NTHR 256
#define NBLKS 512

namespace cfg {
// ws layout in FLOAT units (cells region shrunk vs R13; c1 parity added)
constexpr size_t F_CELLS = 0;          // arr[512] + rel[512*32] u32 (16896 used, 32768 reserved)
constexpr size_t F_H0    = 32768;      // [32][512]
constexpr size_t F_C0    = 49152;      // [32][512]
constexpr size_t F_H1    = 65536;      // [32][512]
constexpr size_t F_C1    = 81920;      // [2][32][512] parity (enc bw writes slot 1)
constexpr size_t F_ATTNS = 114688;     // [2][32][512] attn vector (parity dbuf)
constexpr size_t F_VN    = 147456;     // [512]
constexpr size_t F_ESUM  = 147968;     // [32] exp-sum per row (padded 512)
constexpr size_t F_CTXR  = 148480;     // [32][1024] unnormalized context
constexpr size_t F_AALL  = 181248;     // [128][32][512] attn history
constexpr size_t F_EOUT  = 2278400;    // [32][128][1024] (write-once)
constexpr size_t F_KEYS  = 6472704;    // [32][128][512]  (write-once)
constexpr size_t F_TOTAL = 8569856;    // 34.3 MB (under proven 35.3 MB)
constexpr size_t MEMSET_BYTES = F_VN * 4;  // cells + states (both c1 slots) + attn_s
// gate-partial scratch in the OUT buffer (dead until final projection):
constexpr size_t O_P0 = 0;        // [12][32][2048]
constexpr size_t O_P1 = 786432;   // [16][32][2048]
}

__device__ __forceinline__ float sigm(float x)   { return 1.0f / (1.0f + __expf(-x)); }
__device__ __forceinline__ float tanhft(float x) { return 1.0f - 2.0f / (1.0f + __expf(2.0f * x)); }

// 32-bit agent-scope access — the ONLY uncached primitive (proven)
__device__ __forceinline__ float cload(const float* p) {
  return __hip_atomic_load(p, __ATOMIC_RELAXED, __HIP_MEMORY_SCOPE_AGENT);
}
__device__ __forceinline__ void cstore(float* p, float v) {
  __hip_atomic_store(p, v, __ATOMIC_RELAXED, __HIP_MEMORY_SCOPE_AGENT);
}

// checker/broadcast grid barrier (R4-proven, unchanged)
__device__ __forceinline__ void gbar(unsigned ep, unsigned* arr, unsigned* rel) {
  __syncthreads();
  if (blockIdx.x == 0) {
    if (threadIdx.x == 0)
      __hip_atomic_store(arr, ep, __ATOMIC_RELAXED, __HIP_MEMORY_SCOPE_AGENT);
    int s0 = threadIdx.x, s1 = threadIdx.x + 256;
    while (__hip_atomic_load(arr + s0, __ATOMIC_RELAXED, __HIP_MEMORY_SCOPE_AGENT) < ep)
      __builtin_amdgcn_s_sleep(1);
    while (__hip_atomic_load(arr + s1, __ATOMIC_RELAXED, __HIP_MEMORY_SCOPE_AGENT) < ep)
      __builtin_amdgcn_s_sleep(1);
    __syncthreads();
    __hip_atomic_store(rel + (size_t)s0 * 32, ep, __ATOMIC_RELAXED, __HIP_MEMORY_SCOPE_AGENT);
    __hip_atomic_store(rel + (size_t)s1 * 32, ep, __ATOMIC_RELAXED, __HIP_MEMORY_SCOPE_AGENT);
    __syncthreads();
  } else {
    if (threadIdx.x == 0) {
      __hip_atomic_store(arr + blockIdx.x, ep, __ATOMIC_RELAXED, __HIP_MEMORY_SCOPE_AGENT);
      while (__hip_atomic_load(rel + (size_t)blockIdx.x * 32, __ATOMIC_RELAXED,
                               __HIP_MEMORY_SCOPE_AGENT) < ep)
        __builtin_amdgcn_s_sleep(1);
    }
    __syncthreads();
  }
}

// stage A-tile [32][KWIN] into LDS — gather into regs, then write (R9-proven)
template<int KWIN, typename F>
__device__ __forceinline__ void stage(float* at, F&& f) {
  static_assert((32 * KWIN) % NTHR == 0, "tile must tile NTHR");
  constexpr int PER = (32 * KWIN) / NTHR;
  __syncthreads();
  float v[PER];
#pragma unroll
  for (int r = 0; r < PER; r++) {
    int i = threadIdx.x + NTHR * r;
    v[r] = f(i / KWIN, i % KWIN);
  }
#pragma unroll
  for (int r = 0; r < PER; r++) at[threadIdx.x + NTHR * r] = v[r];
  __syncthreads();
}

// GEMM fragment: preload ALL KQ weight rows (one latency round), then compute (R10-proven)
template<int KWIN>
__device__ __forceinline__ void gemm_frag(const float* __restrict__ W, int ldw,
                                          int n, bool nok, int kw0,
                                          const float* at, float* acc) {
  const int wave = threadIdx.x >> 6;
  constexpr int KQ = KWIN / 4;  // 16..32
  const int klo = wave * KQ;
  const float* wp = W + (size_t)(kw0 + klo) * (size_t)ldw + n;
  float w[KQ];
#pragma unroll
  for (int j = 0; j < KQ; j++) w[j] = nok ? wp[(size_t)j * ldw] : 0.f;
#pragma unroll
  for (int jj = 0; jj < KQ; jj += 4) {
    const float* ap = at + klo + jj;
#pragma unroll
    for (int m = 0; m < 32; m++) {
      float4 a = *(const float4*)(ap + m * KWIN);
      acc[m] = fmaf(a.x, w[jj + 0], acc[m]);
      acc[m] = fmaf(a.y, w[jj + 1], acc[m]);
      acc[m] = fmaf(a.z, w[jj + 2], acc[m]);
      acc[m] = fmaf(a.w, w[jj + 3], acc[m]);
    }
  }
}

// red layout [4][32][64] = 8192 floats (proven)
__device__ __forceinline__ void red_write(float* red, const float* acc) {
  const int wave = threadIdx.x >> 6, lane = threadIdx.x & 63;
  __syncthreads();
#pragma unroll
  for (int m = 0; m < 32; m++) red[(wave * 32 + m) * 64 + lane] = acc[m];
  __syncthreads();
}
__device__ __forceinline__ float redsum(const float* red, int m, int c) {
  return red[m * 64 + c] + red[2048 + m * 64 + c] +
         red[4096 + m * 64 + c] + red[6144 + m * 64 + c];
}

__device__ __forceinline__ void epi_cstore(const float* red, float* outp, int ldo, int n0) {
  for (int i = threadIdx.x; i < 2048; i += NTHR) {
    int m = i >> 6, nn = i & 63;
    cstore(outp + (size_t)m * ldo + n0 + nn, redsum(red, m, nn));
  }
}

// ALL 4 gates x NKB partial loads issued back-to-back, then sum (R10-proven)
template<int NKB>
__device__ __forceinline__ void gate_sum4(const float* base, float g4[4]) {
  float v[4][NKB];
#pragma unroll
  for (int g = 0; g < 4; g++) {
    const float* p = base + g * 512;
#pragma unroll
    for (int j = 0; j < NKB; j++) v[g][j] = cload(p + (size_t)j * 65536);
  }
#pragma unroll
  for (int g = 0; g < 4; g++) {
    float s = 0.f;
#pragma unroll
    for (int j = 0; j < NKB; j++) s += v[g][j];
    g4[g] = s;
  }
}

__global__ __launch_bounds__(NTHR, 2) void seq2seq_kernel(
    const float* __restrict__ embed_in, const float* __restrict__ dec_embed,
    const int* __restrict__ lens,
    const float* __restrict__ Wfw, const float* __restrict__ bfw,
    const float* __restrict__ Wbw, const float* __restrict__ bbw,
    const float* __restrict__ Wd0, const float* __restrict__ bd0,
    const float* __restrict__ Wd1, const float* __restrict__ bd1,
    const float* __restrict__ Wmem, const float* __restrict__ Wq,
    const float* __restrict__ battn, const float* __restrict__ vattn,
    const float* __restrict__ gattn, const float* __restrict__ Wal,
    const float* __restrict__ Wproj, const float* __restrict__ bproj,
    float* __restrict__ out, float* ws) {
  __shared__ float smem[12288];  // 48 KiB: at=[0,4096), red=[4096,12288)
  float* at  = smem;
  float* red = smem + 4096;

  unsigned* arr = (unsigned*)ws;        // [512]
  unsigned* rel = (unsigned*)ws + 512;  // [512*32]
  float* h0     = ws + cfg::F_H0;
  float* c0     = ws + cfg::F_C0;
  float* h1     = ws + cfg::F_H1;
  float* c1     = ws + cfg::F_C1;      // [2][32][512] parity
  float* attn_s = ws + cfg::F_ATTNS;   // parity stride 16384
  float* vn     = ws + cfg::F_VN;
  float* esum   = ws + cfg::F_ESUM;
  float* ctxr   = ws + cfg::F_CTXR;    // [32][1024] unnormalized
  float* aall   = ws + cfg::F_AALL;    // [128][32][512]
  float* eout   = ws + cfg::F_EOUT;
  float* keysp  = ws + cfg::F_KEYS;
  float* p0     = out + cfg::O_P0;     // gate-partial scratch in OUT buffer
  float* p1     = out + cfg::O_P1;

  const int bid = blockIdx.x, tid = threadIdx.x;
  const int wave = tid >> 6, lane = tid & 63;
  unsigned ep = 1;
#define BAR()  do { gbar(ep, arr, rel); ep++; } while (0)
#define BARSEAL() do { __threadfence(); gbar(ep, arr, rel); ep++; __threadfence(); } while (0)

  // ---------------- setup: normalized attention vector ----------------
  if (bid == 0) {
    float s = 0.f;
    for (int u = tid; u < 512; u += NTHR) { float x = vattn[u]; s = fmaf(x, x, s); }
#pragma unroll
    for (int off = 32; off > 0; off >>= 1) s += __shfl_xor(s, off, 64);
    if (lane == 0) at[64 + wave] = s;
    __syncthreads();
    float S = at[64] + at[65] + at[66] + at[67];
    float scale = gattn[0] / sqrtf(S);
    for (int u = tid; u < 512; u += NTHR) vn[u] = vattn[u] * scale;  // plain; sealed below
  }
  BAR();

  // ---------------- bidirectional encoder (R13 structure) ----------------
  for (int t = 0; t < 128; t++) {
    // phase A: fw+bw gate GEMMs: 2dir x 32nb x 8kb = 512 blocks, KWIN=128
    {
      int dir = bid >> 8;
      int r = bid & 255;
      int nb = r & 31, kb = r >> 5;
      const float* W = dir ? Wbw : Wfw;
      const float* hs = dir ? h1 : h0;
      stage<128>(at, [&](int m, int kl) -> float {
        int kk = kb * 128 + kl;
        if (kk < 512) {
          int tt = t;
          if (dir) { int len = lens[m]; tt = (t < len) ? (len - 1 - t) : t; }
          return embed_in[((size_t)m * 128 + tt) * 512 + kk];  // read-only cached
        }
        return cload(hs + m * 512 + kk - 512);
      });
      float acc[32];
#pragma unroll
      for (int m = 0; m < 32; m++) acc[m] = 0.f;
      gemm_frag<128>(W, 2048, nb * 64 + lane, true, kb * 128, at, acc);
      red_write(red, acc);
      epi_cstore(red, (dir ? p1 : p0) + (size_t)kb * 65536, 2048, nb * 64);
    }
    BAR();
    // phase B: activations + masked state update + enc_out write (128 blocks)
    if (bid < 128) {
      int dir = bid >> 6;
      int p = (bid & 63) * NTHR + tid;  // 0..16383
      int m = p >> 9, u = p & 511;
      const float* parts = dir ? p1 : p0;
      const float* bias  = dir ? bbw : bfw;
      float* hs = dir ? h1 : h0;
      float* cs = dir ? (c1 + 16384) : c0;  // enc bw cell lives in c1 slot 1
      float g4[4];
      gate_sum4<8>(parts + m * 2048 + u, g4);
#pragma unroll
      for (int g = 0; g < 4; g++) g4[g] += bias[g * 512 + u];
      int len = lens[m];
      bool valid = t < len;
      float co = cload(cs + m * 512 + u);
      float cn = sigm(g4[2] + 1.f) * co + sigm(g4[0]) * tanhft(g4[1]);
      float hn = sigm(g4[3]) * tanhft(cn);
      if (valid) { cstore(cs + m * 512 + u, cn); cstore(hs + m * 512 + u, hn); }
      int tpos = dir ? (valid ? (len - 1 - t) : t) : t;
      eout[((size_t)m * 128 + tpos) * 1024 + dir * 512 + u] = valid ? hn : 0.f;  // sealed
    }
    BAR();
  }

  BARSEAL();  // seal eout + vn

  // ---------------- keys = enc_out @ w_mem (M=4096, N=512, K=1024) ----------------
  {
#pragma unroll 1
    for (int task = bid; task < 1024; task += NBLKS) {
      int mt = task >> 3, nb = task & 7;
      int n0 = nb * 64;
      const float* arow = eout + (size_t)mt * 32 * 1024;
      float acc[32];
#pragma unroll
      for (int m = 0; m < 32; m++) acc[m] = 0.f;
      const int n = n0 + lane;
#pragma unroll 1
      for (int c = 0; c < 8; c++) {
        stage<128>(at, [&](int m, int kl) -> float {
          return arow[(size_t)m * 1024 + c * 128 + kl];
        });
        gemm_frag<128>(Wmem, 512, n, true, c * 128, at, acc);
      }
      red_write(red, acc);
      for (int i = tid; i < 2048; i += NTHR) {
        int m = i >> 6, nn = i & 63;
        keysp[(size_t)mt * 32 * 512 + (size_t)m * 512 + n0 + nn] = redsum(red, m, nn);
      }
    }
  }
  BARSEAL();  // seal keys

  // ---------------- decoder loop (5 phases/step; projection deferred) ----------------
  for (int t = 0; t < 128; t++) {
    // phase A: gates0 GEMM, K=1536; 32nb x 12kb = 384 blocks, KWIN=128
    //          || blocks 384..391: copy attn(t-1) -> aall[t-1]
    if (bid < 384) {
      int nb = bid & 31, kb = bid >> 5;  // kb 0..11
      const float* asrc = attn_s + (size_t)((t + 1) & 1) * 16384;  // attn(t-1)
      stage<128>(at, [&](int m, int kl) -> float {
        int kk = kb * 128 + kl;
        if (kk < 512) return dec_embed[((size_t)m * 128 + t) * 512 + kk];
        if (kk < 1024) return cload(asrc + m * 512 + kk - 512);
        return cload(h0 + m * 512 + kk - 1024);
      });
      float acc[32];
#pragma unroll
      for (int m = 0; m < 32; m++) acc[m] = 0.f;
      gemm_frag<128>(Wd0, 2048, nb * 64 + lane, true, kb * 128, at, acc);
      red_write(red, acc);
      epi_cstore(red, p0 + (size_t)kb * 65536, 2048, nb * 64);
    } else if (bid < 392 && t >= 1) {
      const float* asrc = attn_s + (size_t)((t + 1) & 1) * 16384;  // attn(t-1)
      float v[8];
      int j8 = ((bid - 384) * 256 + tid) * 8;
#pragma unroll
      for (int k = 0; k < 8; k++) v[k] = cload(asrc + j8 + k);
#pragma unroll
      for (int k = 0; k < 8; k++) aall[(size_t)(t - 1) * 16384 + j8 + k] = v[k];
    }
    BAR();

    // phase B: act0 (0..63) + zero attn_s[t&1] (64..71) + zero ctxr/esum (72..79)
    if (bid < 64) {
      int p = bid * NTHR + tid;
      int m = p >> 9, u = p & 511;
      float g4[4];
      gate_sum4<12>(p0 + m * 2048 + u, g4);
#pragma unroll
      for (int g = 0; g < 4; g++) g4[g] += bd0[g * 512 + u];
      float co = cload(c0 + m * 512 + u);
      float cn = sigm(g4[2] + 1.f) * co + sigm(g4[0]) * tanhft(g4[1]);
      float hn = sigm(g4[3]) * tanhft(cn);
      cstore(c0 + m * 512 + u, cn);
      cstore(h0 + m * 512 + u, hn);
    } else if (bid < 72) {
      float* az = attn_s + (size_t)(t & 1) * 16384 + (size_t)(bid - 64) * 2048;
      for (int i = tid; i < 2048; i += NTHR) cstore(az + i, 0.f);
    } else if (bid < 80) {
      float* cz = ctxr + (size_t)(bid - 72) * 4096;
      for (int i = tid; i < 4096; i += NTHR) cstore(cz + i, 0.f);
      if (bid == 72 && tid < 32) cstore(esum + tid, 0.f);
    }
    BAR();

    // phase C: gates1 GEMM, K=1024 = h0new|h1old; 32nb x 16kb, KWIN=64
    {
      int nb = bid & 31, kb = bid >> 5;
      stage<64>(at, [&](int m, int kl) -> float {
        int kk = kb * 64 + kl;
        return (kk < 512) ? cload(h0 + m * 512 + kk) : cload(h1 + m * 512 + kk - 512);
      });
      float acc[32];
#pragma unroll
      for (int m = 0; m < 32; m++) acc[m] = 0.f;
      gemm_frag<64>(Wd1, 2048, nb * 64 + lane, true, kb * 64, at, acc);
      red_write(red, acc);
      epi_cstore(red, p1 + (size_t)kb * 65536, 2048, nb * 64);
    }
    BAR();

    // phase E: flash-style attention, 256 blocks: (b, sub) — sub owns 16 t-rows.
    // |score| <= ||vn||_1 <= 1 (tanh in [-1,1], vn normalized) -> max-free exp.
    if (bid < 256) {
      const int b = bid >> 3, sub = bid & 7;
      const int len = lens[b];
      float* sh_h1v = at;          // 512
      float* sh_qb  = at + 512;    // 512
      float* sh_vnv = at + 1024;   // 512
      float* sh_e   = at + 1536;   // 16
      float* redq   = at + 2048;   // 2048
      const float* c1r = c1 + (size_t)((t + 1) & 1) * 16384;
      float* c1w = c1 + (size_t)(t & 1) * 16384;
      // act1 (redundant across the 8 subs; sub 0 publishes h1/c1)
#pragma unroll 1
      for (int u = tid; u < 512; u += NTHR) {
        float g4[4];
        gate_sum4<16>(p1 + b * 2048 + u, g4);
#pragma unroll
        for (int g = 0; g < 4; g++) g4[g] += bd1[g * 512 + u];
        float co = cload(c1r + b * 512 + u);
        float cn = sigm(g4[2] + 1.f) * co + sigm(g4[0]) * tanhft(g4[1]);
        float hn = sigm(g4[3]) * tanhft(cn);
        if (sub == 0) {
          cstore(c1w + b * 512 + u, cn);
          cstore(h1 + b * 512 + u, hn);
        }
        sh_h1v[u] = hn;
        sh_vnv[u] = vn[u];
      }
      __syncthreads();
      // q = h1n @ w_query — batched x8 (redundant across subs)
      {
        float4 qa = make_float4(0.f, 0.f, 0.f, 0.f), qb4 = make_float4(0.f, 0.f, 0.f, 0.f);
        const int ua = lane * 4, ub = 256 + lane * 4;
        const float* wqp = Wq + (size_t)(wave * 128) * 512;
#pragma unroll 1
        for (int kk = 0; kk < 128; kk += 8) {
          float4 wa[8], wb[8];
#pragma unroll
          for (int j = 0; j < 8; j++) {
            wa[j] = *(const float4*)(wqp + (size_t)(kk + j) * 512 + ua);
            wb[j] = *(const float4*)(wqp + (size_t)(kk + j) * 512 + ub);
          }
#pragma unroll
          for (int j = 0; j < 8; j++) {
            float h = sh_h1v[wave * 128 + kk + j];
            qa.x = fmaf(h, wa[j].x, qa.x); qa.y = fmaf(h, wa[j].y, qa.y);
            qa.z = fmaf(h, wa[j].z, qa.z); qa.w = fmaf(h, wa[j].w, qa.w);
            qb4.x = fmaf(h, wb[j].x, qb4.x); qb4.y = fmaf(h, wb[j].y, qb4.y);
            qb4.z = fmaf(h, wb[j].z, qb4.z); qb4.w = fmaf(h, wb[j].w, qb4.w);
          }
        }
        *(float4*)(redq + wave * 512 + ua) = qa;
        *(float4*)(redq + wave * 512 + ub) = qb4;
      }
      __syncthreads();
      for (int u = tid; u < 512; u += NTHR)
        sh_qb[u] = redq[u] + redq[512 + u] + redq[1024 + u] + redq[1536 + u] + battn[u];
      __syncthreads();
      // scores for this sub's 16 rows: wave handles 4 (batched loads, one round)
      {
        float4 kv[4][2];
#pragma unroll
        for (int j = 0; j < 4; j++) {
          const float* kp = keysp + ((size_t)b * 128 + sub * 16 + wave * 4 + j) * 512;
          kv[j][0] = *(const float4*)(kp + lane * 4);
          kv[j][1] = *(const float4*)(kp + lane * 4 + 256);
        }
#pragma unroll
        for (int j = 0; j < 4; j++) {
          int tq = sub * 16 + wave * 4 + j;
          float s = 0.f;
#pragma unroll
          for (int hh = 0; hh < 2; hh++) {
            int u = lane * 4 + hh * 256;
            float4 k4 = kv[j][hh];
            s += sh_vnv[u + 0] * tanhft(k4.x + sh_qb[u + 0]);
            s += sh_vnv[u + 1] * tanhft(k4.y + sh_qb[u + 1]);
            s += sh_vnv[u + 2] * tanhft(k4.z + sh_qb[u + 2]);
            s += sh_vnv[u + 3] * tanhft(k4.w + sh_qb[u + 3]);
          }
#pragma unroll
          for (int off = 32; off > 0; off >>= 1) s += __shfl_xor(s, off, 64);
          if (lane == 0) sh_e[wave * 4 + j] = (tq < len) ? __expf(s) : 0.f;
        }
      }
      __syncthreads();
      if (tid == 0) {
        float es = 0.f;
#pragma unroll
        for (int i = 0; i < 16; i++) es += sh_e[i];
        atomicAdd(esum + b, es);
      }
      // context partial: thread owns 4 d-cols; 16 eout rows batched (one round)
      {
        int d = tid * 4;
        const float* ep2 = eout + ((size_t)b * 128 + sub * 16) * 1024 + d;
        float4 e4[16];
#pragma unroll
        for (int j = 0; j < 16; j++)
          e4[j] = *(const float4*)(ep2 + (size_t)j * 1024);
        float4 acc = make_float4(0.f, 0.f, 0.f, 0.f);
#pragma unroll
        for (int j = 0; j < 16; j++) {
          float a = sh_e[j];
          acc.x = fmaf(a, e4[j].x, acc.x); acc.y = fmaf(a, e4[j].y, acc.y);
          acc.z = fmaf(a, e4[j].z, acc.z); acc.w = fmaf(a, e4[j].w, acc.w);
        }
        float* cp = ctxr + (size_t)b * 1024 + d;
        atomicAdd(cp + 0, acc.x);
        atomicAdd(cp + 1, acc.y);
        atomicAdd(cp + 2, acc.z);
        atomicAdd(cp + 3, acc.w);
      }
    }
    BAR();

    // phase F: attn(t) = (h1|ctx) @ Wal; 8nb x 16kb = 128 blocks, KWIN=96
    // ctx normalized on the fly: ctxr/esum
    if (bid < 128) {
      int nb = bid & 7, kb = bid >> 3;
      stage<96>(at, [&](int m, int kl) -> float {
        int kk = kb * 96 + kl;
        if (kk < 512) return cload(h1 + m * 512 + kk);
        float inv = 1.0f / cload(esum + m);
        return cload(ctxr + (size_t)m * 1024 + kk - 512) * inv;
      });
      float acc[32];
#pragma unroll
      for (int m = 0; m < 32; m++) acc[m] = 0.f;
      gemm_frag<96>(Wal, 512, nb * 64 + lane, true, kb * 96, at, acc);
      red_write(red, acc);
      float* adst = attn_s + (size_t)(t & 1) * 16384;
      for (int i = tid; i < 2048; i += NTHR) {
        int m = i >> 6, nn = i & 63;
        atomicAdd(adst + (size_t)m * 512 + nb * 64 + nn, redsum(red, m, nn));
      }
    }
    BAR();
  }

  // trailing copy: attn(127) -> aall[127]  (parity slot 127&1 = 1)
  if (bid >= 384 && bid < 392) {
    const float* asrc = attn_s + (size_t)1 * 16384;
    float v[8];
    int j8 = ((bid - 384) * 256 + tid) * 8;
#pragma unroll
    for (int k = 0; k < 8; k++) v[k] = cload(asrc + j8 + k);
#pragma unroll
    for (int k = 0; k < 8; k++) aall[(size_t)127 * 16384 + j8 + k] = v[k];
  }
  BARSEAL();  // seal aall; p0/p1 scratch now dead

  // ---------------- batched projection: out = aall @ Wproj + bproj ----------------
#pragma unroll 1
  for (int task = bid; task < 564; task += NBLKS) {
    int nb = task >> 2, tq = task & 3;  // nb 0..140, tq 0..3
    int n0 = nb * 64;
    const int col = n0 + lane;
    const bool ok = col < 9000;
#pragma unroll 1
    for (int t = tq * 32; t < tq * 32 + 32; t++) {
      const float* asrc = aall + (size_t)t * 16384;
      float acc[32];
#pragma unroll
      for (int m = 0; m < 32; m++) acc[m] = 0.f;
#pragma unroll 1
      for (int c = 0; c < 4; c++) {
        stage<128>(at, [&](int m, int kl) -> float {
          return asrc[(size_t)m * 512 + c * 128 + kl];  // plain cached (sealed)
        });
        gemm_frag<128>(Wproj, 9000, col, ok, c * 128, at, acc);
      }
      red_write(red, acc);
      for (int i = tid; i < 2048; i += NTHR) {
        int m = i >> 6, nn = i & 63;
        int nc = n0 + nn;
        if (nc < 9000)
          out[((size_t)m * 128 + t) * 9000 + nc] = redsum(red, m, nn) + bproj[nc];
      }
    }
  }
#undef BAR
#undef BARSEAL
}

extern "C" void kernel_launch(void* const* d_in, const int* in_sizes, int n_in,
                              void* d_out, int out_size, void* d_ws, size_t ws_size,
                              hipStream_t stream) {
  (void)in_sizes; (void)n_in; (void)out_size; (void)ws_size;
  hipMemsetAsync(d_ws, 0, cfg::MEMSET_BYTES, stream);  // cells + states + attn_s
  hipLaunchKernelGGL(seq2seq_kernel, dim3(NBLKS), dim3(NTHR), 0, stream,
                     (const float*)d_in[0],   // embed_in
                     (const float*)d_in[1],   // dec_embed
                     (const int*)d_in[2],     // in_seq_len
                     (const float*)d_in[3],   // enc_fw_kernel
                     (const float*)d_in[4],   // enc_fw_bias
                     (const float*)d_in[5],   // enc_bw_kernel
                     (const float*)d_in[6],   // enc_bw_bias
                     (const float*)d_in[7],   // dec_kernel0
                     (const float*)d_in[8],   // dec_bias0
                     (const float*)d_in[9],   // dec_kernel1
                     (const float*)d_in[10],  // dec_bias1
                     (const float*)d_in[11],  // w_mem
                     (const float*)d_in[12],  // w_query
                     (const float*)d_in[13],  // b_attn
                     (const float*)d_in[14],  // v_attn
                     (const float*)d_in[15],  // g_attn
                     (const float*)d_in[16],  // w_attn_layer
                     (const float*)d_in[17],  // w_proj
                     (const float*)d_in[18],  // b_proj
                     (float*)d_out, (float*)d_ws);
}

// Round 17
// 16188.161 us; speedup vs baseline: 2.2632x; 1.1362x over previous
//
#include <hip/hip_runtime.h>
#include <stdint.h>

#define NTHR 256
#define NBLKS 512

namespace cfg {
// ws layout in FLOAT units
constexpr size_t F_CELLS = 0;          // arr[512] + rel[512*32] u32
constexpr size_t F_H0    = 32768;      // [32][512]
constexpr size_t F_C0    = 49152;      // [32][512]
constexpr size_t F_H1    = 65536;      // [32][512]
constexpr size_t F_C1    = 81920;      // [2][32][512] parity (enc bw writes slot 1)
constexpr size_t F_H1W   = 114688;     // [2][32][512] h1 @ Wal0 (parity)
constexpr size_t F_EATTN = 147456;     // [2][32][512] e-weighted eoutWal acc (parity)
constexpr size_t F_ESUM  = 180224;     // [2][32] pad to 1024
constexpr size_t F_VN    = 181248;     // [512]
constexpr size_t F_AALL  = 181760;     // [128][32][512] attn history
constexpr size_t F_EOUT  = 2278912;    // [32][128][1024] (write-once)
constexpr size_t F_KEYS  = 6473216;    // [32][128][512]  (write-once)
constexpr size_t F_TOTAL = 8570368;    // 34.3 MB
constexpr size_t MEMSET_BYTES = F_VN * 4;  // cells + all states/accumulators
// scratch in OUT buffer (dead until final projection):
constexpr size_t O_P0    = 0;          // [8][32][2048]
constexpr size_t O_P1    = 524288;     // [8][32][2048] (0..3 h0-part, 4..7 h1-part)
constexpr size_t O_XGFW  = 1048576;    // [128][32][2048] enc fw x-gates
constexpr size_t O_XGBW  = 9437184;    // [128][32][2048] enc bw x-gates
constexpr size_t O_XGD0  = 17825792;   // [128][32][2048] dec0 x-gates
constexpr size_t O_EOWAL = 26214400;   // [32][128][512] eout @ Wal1
}

__device__ __forceinline__ float sigm(float x)   { return 1.0f / (1.0f + __expf(-x)); }
__device__ __forceinline__ float tanhft(float x) { return 1.0f - 2.0f / (1.0f + __expf(2.0f * x)); }

__device__ __forceinline__ float cload(const float* p) {
  return __hip_atomic_load(p, __ATOMIC_RELAXED, __HIP_MEMORY_SCOPE_AGENT);
}
__device__ __forceinline__ void cstore(float* p, float v) {
  __hip_atomic_store(p, v, __ATOMIC_RELAXED, __HIP_MEMORY_SCOPE_AGENT);
}

// checker/broadcast grid barrier (R4-proven)
__device__ __forceinline__ void gbar(unsigned ep, unsigned* arr, unsigned* rel) {
  __syncthreads();
  if (blockIdx.x == 0) {
    if (threadIdx.x == 0)
      __hip_atomic_store(arr, ep, __ATOMIC_RELAXED, __HIP_MEMORY_SCOPE_AGENT);
    int s0 = threadIdx.x, s1 = threadIdx.x + 256;
    while (__hip_atomic_load(arr + s0, __ATOMIC_RELAXED, __HIP_MEMORY_SCOPE_AGENT) < ep)
      __builtin_amdgcn_s_sleep(1);
    while (__hip_atomic_load(arr + s1, __ATOMIC_RELAXED, __HIP_MEMORY_SCOPE_AGENT) < ep)
      __builtin_amdgcn_s_sleep(1);
    __syncthreads();
    __hip_atomic_store(rel + (size_t)s0 * 32, ep, __ATOMIC_RELAXED, __HIP_MEMORY_SCOPE_AGENT);
    __hip_atomic_store(rel + (size_t)s1 * 32, ep, __ATOMIC_RELAXED, __HIP_MEMORY_SCOPE_AGENT);
    __syncthreads();
  } else {
    if (threadIdx.x == 0) {
      __hip_atomic_store(arr + blockIdx.x, ep, __ATOMIC_RELAXED, __HIP_MEMORY_SCOPE_AGENT);
      while (__hip_atomic_load(rel + (size_t)blockIdx.x * 32, __ATOMIC_RELAXED,
                               __HIP_MEMORY_SCOPE_AGENT) < ep)
        __builtin_amdgcn_s_sleep(1);
    }
    __syncthreads();
  }
}

// stage A-tile [32][KWIN] into LDS (R9-proven)
template<int KWIN, typename F>
__device__ __forceinline__ void stage(float* at, F&& f) {
  static_assert((32 * KWIN) % NTHR == 0, "tile must tile NTHR");
  constexpr int PER = (32 * KWIN) / NTHR;
  __syncthreads();
  float v[PER];
#pragma unroll
  for (int r = 0; r < PER; r++) {
    int i = threadIdx.x + NTHR * r;
    v[r] = f(i / KWIN, i % KWIN);
  }
#pragma unroll
  for (int r = 0; r < PER; r++) at[threadIdx.x + NTHR * r] = v[r];
  __syncthreads();
}

// GEMM fragment (R10-proven)
template<int KWIN>
__device__ __forceinline__ void gemm_frag(const float* __restrict__ W, int ldw,
                                          int n, bool nok, int kw0,
                                          const float* at, float* acc) {
  const int wave = threadIdx.x >> 6;
  constexpr int KQ = KWIN / 4;
  const int klo = wave * KQ;
  const float* wp = W + (size_t)(kw0 + klo) * (size_t)ldw + n;
  float w[KQ];
#pragma unroll
  for (int j = 0; j < KQ; j++) w[j] = nok ? wp[(size_t)j * ldw] : 0.f;
#pragma unroll
  for (int jj = 0; jj < KQ; jj += 4) {
    const float* ap = at + klo + jj;
#pragma unroll
    for (int m = 0; m < 32; m++) {
      float4 a = *(const float4*)(ap + m * KWIN);
      acc[m] = fmaf(a.x, w[jj + 0], acc[m]);
      acc[m] = fmaf(a.y, w[jj + 1], acc[m]);
      acc[m] = fmaf(a.z, w[jj + 2], acc[m]);
      acc[m] = fmaf(a.w, w[jj + 3], acc[m]);
    }
  }
}

__device__ __forceinline__ void red_write(float* red, const float* acc) {
  const int wave = threadIdx.x >> 6, lane = threadIdx.x & 63;
  __syncthreads();
#pragma unroll
  for (int m = 0; m < 32; m++) red[(wave * 32 + m) * 64 + lane] = acc[m];
  __syncthreads();
}
__device__ __forceinline__ float redsum(const float* red, int m, int c) {
  return red[m * 64 + c] + red[2048 + m * 64 + c] +
         red[4096 + m * 64 + c] + red[6144 + m * 64 + c];
}

__device__ __forceinline__ void epi_cstore(const float* red, float* outp, int ldo, int n0) {
  for (int i = threadIdx.x; i < 2048; i += NTHR) {
    int m = i >> 6, nn = i & 63;
    cstore(outp + (size_t)m * ldo + n0 + nn, redsum(red, m, nn));
  }
}
__device__ __forceinline__ void epi_plain(const float* red, float* outp, int ldo, int n0) {
  for (int i = threadIdx.x; i < 2048; i += NTHR) {
    int m = i >> 6, nn = i & 63;
    outp[(size_t)m * ldo + n0 + nn] = redsum(red, m, nn);
  }
}

template<int NKB>
__device__ __forceinline__ void gate_sum4(const float* base, float g4[4]) {
  float v[4][NKB];
#pragma unroll
  for (int g = 0; g < 4; g++) {
    const float* p = base + g * 512;
#pragma unroll
    for (int j = 0; j < NKB; j++) v[g][j] = cload(p + (size_t)j * 65536);
  }
#pragma unroll
  for (int g = 0; g < 4; g++) {
    float s = 0.f;
#pragma unroll
    for (int j = 0; j < NKB; j++) s += v[g][j];
    g4[g] = s;
  }
}

__global__ __launch_bounds__(NTHR, 2) void seq2seq_kernel(
    const float* __restrict__ embed_in, const float* __restrict__ dec_embed,
    const int* __restrict__ lens,
    const float* __restrict__ Wfw, const float* __restrict__ bfw,
    const float* __restrict__ Wbw, const float* __restrict__ bbw,
    const float* __restrict__ Wd0, const float* __restrict__ bd0,
    const float* __restrict__ Wd1, const float* __restrict__ bd1,
    const float* __restrict__ Wmem, const float* __restrict__ Wq,
    const float* __restrict__ battn, const float* __restrict__ vattn,
    const float* __restrict__ gattn, const float* __restrict__ Wal,
    const float* __restrict__ Wproj, const float* __restrict__ bproj,
    float* __restrict__ out, float* ws) {
  __shared__ float smem[12288];  // 48 KiB: at=[0,4096), red=[4096,12288)
  float* at  = smem;
  float* red = smem + 4096;

  unsigned* arr = (unsigned*)ws;
  unsigned* rel = (unsigned*)ws + 512;
  float* h0     = ws + cfg::F_H0;
  float* c0     = ws + cfg::F_C0;
  float* h1     = ws + cfg::F_H1;
  float* c1     = ws + cfg::F_C1;      // [2] parity
  float* h1w    = ws + cfg::F_H1W;     // [2] parity, stride 16384
  float* eattn  = ws + cfg::F_EATTN;   // [2] parity, stride 16384
  float* esum   = ws + cfg::F_ESUM;    // [2] parity, stride 512
  float* vn     = ws + cfg::F_VN;
  float* aall   = ws + cfg::F_AALL;
  float* eout   = ws + cfg::F_EOUT;
  float* keysp  = ws + cfg::F_KEYS;
  float* p0     = out + cfg::O_P0;
  float* p1     = out + cfg::O_P1;
  float* xgfw   = out + cfg::O_XGFW;
  float* xgbw   = out + cfg::O_XGBW;
  float* xgd0   = out + cfg::O_XGD0;
  float* eoWal  = out + cfg::O_EOWAL;

  const int bid = blockIdx.x, tid = threadIdx.x;
  const int wave = tid >> 6, lane = tid & 63;
  unsigned ep = 1;
#define BAR()  do { gbar(ep, arr, rel); ep++; } while (0)
#define BARSEAL() do { __threadfence(); gbar(ep, arr, rel); ep++; __threadfence(); } while (0)

  // attn(t') reconstruction: h1w + eattn/esum (parity slot pre-offset pointers)
  auto attn_of = [&](const float* h1w_p, const float* ea_p, const float* es_p,
                     int m, int u) -> float {
    float es = cload(es_p + m);
    float inv = es > 0.f ? 1.f / es : 0.f;
    return cload(h1w_p + m * 512 + u) + cload(ea_p + m * 512 + u) * inv;
  };

  // ---------------- setup: normalized attention vector (block 0) ----------------
  if (bid == 0) {
    float s = 0.f;
    for (int u = tid; u < 512; u += NTHR) { float x = vattn[u]; s = fmaf(x, x, s); }
#pragma unroll
    for (int off = 32; off > 0; off >>= 1) s += __shfl_xor(s, off, 64);
    if (lane == 0) at[64 + wave] = s;
    __syncthreads();
    float S = at[64] + at[65] + at[66] + at[67];
    float scale = gattn[0] / sqrtf(S);
    for (int u = tid; u < 512; u += NTHR) vn[u] = vattn[u] * scale;  // sealed below
    __syncthreads();
  }

  // ---------------- upfront: x-gate precompute (no barriers inside) ----------------
  // xg[mat][t][m][2048] = x[m][t] @ Wmat[0:512];  mats: fw, bw, dec0
#pragma unroll 1
  for (int task = bid; task < 12288; task += NBLKS) {
    int mat = task >> 12;          // 0 fw, 1 bw, 2 dec0
    int r = task & 4095;
    int tt = r >> 5, nb = r & 31;
    const float* X = (mat == 2) ? dec_embed : embed_in;
    const float* W = (mat == 0) ? Wfw : (mat == 1) ? Wbw : Wd0;
    float* dst = ((mat == 0) ? xgfw : (mat == 1) ? xgbw : xgd0) + (size_t)tt * 65536;
    float acc[32];
#pragma unroll
    for (int m = 0; m < 32; m++) acc[m] = 0.f;
#pragma unroll 1
    for (int c = 0; c < 4; c++) {
      stage<128>(at, [&](int m, int kl) -> float {
        return X[((size_t)m * 128 + tt) * 512 + c * 128 + kl];
      });
      gemm_frag<128>(W, 2048, nb * 64 + lane, true, c * 128, at, acc);
    }
    red_write(red, acc);
    epi_plain(red, dst, 2048, nb * 64);
  }
  BARSEAL();  // seal vn + xg

  // ---------------- bidirectional encoder: 2 phases/step ----------------
  for (int t = 0; t < 128; t++) {
    // phase A: h-part gate GEMMs only (K=512): 2dir x 32nb x 4kb = 256 blocks
    if (bid < 256) {
      int dir = bid >> 7;
      int r = bid & 127;
      int nb = r & 31, kb = r >> 5;  // kb 0..3
      const float* W = dir ? Wbw : Wfw;
      const float* hs = dir ? h1 : h0;
      stage<128>(at, [&](int m, int kl) -> float {
        return cload(hs + m * 512 + kb * 128 + kl);
      });
      float acc[32];
#pragma unroll
      for (int m = 0; m < 32; m++) acc[m] = 0.f;
      gemm_frag<128>(W, 2048, nb * 64 + lane, true, 512 + kb * 128, at, acc);
      red_write(red, acc);
      epi_cstore(red, (dir ? p1 : p0) + (size_t)kb * 65536, 2048, nb * 64);
    }
    BAR();
    // phase B: activations (xg cached) + masked update + eout (128 blocks)
    if (bid < 128) {
      int dir = bid >> 6;
      int p = (bid & 63) * NTHR + tid;
      int m = p >> 9, u = p & 511;
      const float* parts = dir ? p1 : p0;
      const float* bias  = dir ? bbw : bfw;
      float* hs = dir ? h1 : h0;
      float* cs = dir ? (c1 + 16384) : c0;  // enc bw cell in c1 slot 1
      int len = lens[m];
      bool valid = t < len;
      int tt = dir ? ((t < len) ? (len - 1 - t) : t) : t;
      const float* xg = (dir ? xgbw : xgfw) + (size_t)tt * 65536 + m * 2048;
      float g4[4];
      gate_sum4<4>(parts + m * 2048 + u, g4);
#pragma unroll
      for (int g = 0; g < 4; g++) g4[g] += xg[g * 512 + u] + bias[g * 512 + u];
      float co = cload(cs + m * 512 + u);
      float cn = sigm(g4[2] + 1.f) * co + sigm(g4[0]) * tanhft(g4[1]);
      float hn = sigm(g4[3]) * tanhft(cn);
      if (valid) { cstore(cs + m * 512 + u, cn); cstore(hs + m * 512 + u, hn); }
      int tpos = dir ? (valid ? (len - 1 - t) : t) : t;
      eout[((size_t)m * 128 + tpos) * 1024 + dir * 512 + u] = valid ? hn : 0.f;
    }
    BAR();
  }
  BARSEAL();  // seal eout

  // ---------------- keys + eoutWal (2048 tasks, one sealed section) ----------------
#pragma unroll 1
  for (int task = bid; task < 2048; task += NBLKS) {
    if (task < 1024) {  // keys = eout @ Wmem
      int mt = task >> 3, nb = task & 7;
      const float* arow = eout + (size_t)mt * 32 * 1024;
      float acc[32];
#pragma unroll
      for (int m = 0; m < 32; m++) acc[m] = 0.f;
#pragma unroll 1
      for (int c = 0; c < 8; c++) {
        stage<128>(at, [&](int m, int kl) -> float {
          return arow[(size_t)m * 1024 + c * 128 + kl];
        });
        gemm_frag<128>(Wmem, 512, nb * 64 + lane, true, c * 128, at, acc);
      }
      red_write(red, acc);
      epi_plain(red, keysp + (size_t)mt * 32 * 512, 512, nb * 64);
    } else {  // eoutWal = eout @ Wal[512:1536]
      int t2 = task - 1024;
      int mt = t2 >> 3, nb = t2 & 7;
      const float* arow = eout + (size_t)mt * 32 * 1024;
      float acc[32];
#pragma unroll
      for (int m = 0; m < 32; m++) acc[m] = 0.f;
#pragma unroll 1
      for (int c = 0; c < 8; c++) {
        stage<128>(at, [&](int m, int kl) -> float {
          return arow[(size_t)m * 1024 + c * 128 + kl];
        });
        gemm_frag<128>(Wal, 512, nb * 64 + lane, true, 512 + c * 128, at, acc);
      }
      red_write(red, acc);
      epi_plain(red, eoWal + (size_t)mt * 32 * 512, 512, nb * 64);
    }
  }
  BARSEAL();  // seal keys + eoutWal

  // ---------------- decoder loop: 4 phases/step ----------------
  for (int t = 0; t < 128; t++) {
    const float* h1w_p = h1w + (size_t)((t + 1) & 1) * 16384;   // attn(t-1) pieces
    const float* ea_p  = eattn + (size_t)((t + 1) & 1) * 16384;
    const float* es_p  = esum + (size_t)((t + 1) & 1) * 512;

    // phase A: gates0 GEMM K=1024 (attn-reconstructed | h0), 256 blocks
    //          + gates1 h1-part K=512, 128 blocks (256..383)
    //          + aall[t-1] reconstruction, 8 blocks (384..391)
    if (bid < 256) {
      int nb = bid & 31, kb = bid >> 5;  // kb 0..7
      stage<128>(at, [&](int m, int kl) -> float {
        int kk = kb * 128 + kl;
        if (kk < 512) return attn_of(h1w_p, ea_p, es_p, m, kk);
        return cload(h0 + m * 512 + kk - 512);
      });
      float acc[32];
#pragma unroll
      for (int m = 0; m < 32; m++) acc[m] = 0.f;
      gemm_frag<128>(Wd0, 2048, nb * 64 + lane, true, 512 + kb * 128, at, acc);
      red_write(red, acc);
      epi_cstore(red, p0 + (size_t)kb * 65536, 2048, nb * 64);
    } else if (bid < 384) {
      int idx = bid - 256;
      int nb = idx & 31, kb = idx >> 5;  // kb 0..3
      stage<128>(at, [&](int m, int kl) -> float {
        return cload(h1 + m * 512 + kb * 128 + kl);
      });
      float acc[32];
#pragma unroll
      for (int m = 0; m < 32; m++) acc[m] = 0.f;
      gemm_frag<128>(Wd1, 2048, nb * 64 + lane, true, 512 + kb * 128, at, acc);
      red_write(red, acc);
      epi_cstore(red, p1 + (size_t)(4 + kb) * 65536, 2048, nb * 64);
    } else if (bid < 392 && t >= 1) {
      int j = (bid - 384) * 256 + tid;  // 0..2047 over [32][64] pieces
      int m = j >> 6, u0 = (j & 63) * 8;
      float v[8];
#pragma unroll
      for (int k = 0; k < 8; k++) v[k] = attn_of(h1w_p, ea_p, es_p, m, u0 + k);
#pragma unroll
      for (int k = 0; k < 8; k++) aall[(size_t)(t - 1) * 16384 + m * 512 + u0 + k] = v[k];
    }
    BAR();

    // phase B: act0 (0..63) + zero eattn/esum[t&1] (64..71)
    if (bid < 64) {
      int p = bid * NTHR + tid;
      int m = p >> 9, u = p & 511;
      const float* xg = xgd0 + (size_t)t * 65536 + m * 2048;
      float g4[4];
      gate_sum4<8>(p0 + m * 2048 + u, g4);
#pragma unroll
      for (int g = 0; g < 4; g++) g4[g] += xg[g * 512 + u] + bd0[g * 512 + u];
      float co = cload(c0 + m * 512 + u);
      float cn = sigm(g4[2] + 1.f) * co + sigm(g4[0]) * tanhft(g4[1]);
      float hn = sigm(g4[3]) * tanhft(cn);
      cstore(c0 + m * 512 + u, cn);
      cstore(h0 + m * 512 + u, hn);
    } else if (bid < 72) {
      float* az = eattn + (size_t)(t & 1) * 16384 + (size_t)(bid - 64) * 2048;
      for (int i = tid; i < 2048; i += NTHR) cstore(az + i, 0.f);
      if (bid == 64 && tid < 32) cstore(esum + (size_t)(t & 1) * 512 + tid, 0.f);
    }
    BAR();

    // phase C: gates1 h0-part K=512: 32nb x 4kb = 128 blocks
    if (bid < 128) {
      int nb = bid & 31, kb = bid >> 5;  // kb 0..3
      stage<128>(at, [&](int m, int kl) -> float {
        return cload(h0 + m * 512 + kb * 128 + kl);
      });
      float acc[32];
#pragma unroll
      for (int m = 0; m < 32; m++) acc[m] = 0.f;
      gemm_frag<128>(Wd1, 2048, nb * 64 + lane, true, kb * 128, at, acc);
      red_write(red, acc);
      epi_cstore(red, p1 + (size_t)kb * 65536, 2048, nb * 64);
    }
    BAR();

    // phase E: flash attention + attn-piece production (256 blocks: b x sub)
    if (bid < 256) {
      const int b = bid >> 3, sub = bid & 7;
      const int len = lens[b];
      float* sh_h1v = at;          // 512
      float* sh_qb  = at + 512;    // 512
      float* sh_vnv = at + 1024;   // 512
      float* sh_e   = at + 1536;   // 16
      float* sh_hw  = at + 1568;   // 256 (h1w k-partials)
      float* redq   = at + 2048;   // 2048
      const float* c1r = c1 + (size_t)((t + 1) & 1) * 16384;
      float* c1w = c1 + (size_t)(t & 1) * 16384;
      float* h1w_w = h1w + (size_t)(t & 1) * 16384;
      float* ea_w  = eattn + (size_t)(t & 1) * 16384;
      float* es_w  = esum + (size_t)(t & 1) * 512;
      // act1 (redundant across subs; sub 0 publishes h1/c1)
#pragma unroll 1
      for (int u = tid; u < 512; u += NTHR) {
        float g4[4];
        gate_sum4<8>(p1 + b * 2048 + u, g4);
#pragma unroll
        for (int g = 0; g < 4; g++) g4[g] += bd1[g * 512 + u];
        float co = cload(c1r + b * 512 + u);
        float cn = sigm(g4[2] + 1.f) * co + sigm(g4[0]) * tanhft(g4[1]);
        float hn = sigm(g4[3]) * tanhft(cn);
        if (sub == 0) {
          cstore(c1w + b * 512 + u, cn);
          cstore(h1 + b * 512 + u, hn);
        }
        sh_h1v[u] = hn;
        sh_vnv[u] = vn[u];
      }
      __syncthreads();
      // q = h1n @ w_query — batched x8 (redundant across subs)
      {
        float4 qa = make_float4(0.f, 0.f, 0.f, 0.f), qb4 = make_float4(0.f, 0.f, 0.f, 0.f);
        const int ua = lane * 4, ub = 256 + lane * 4;
        const float* wqp = Wq + (size_t)(wave * 128) * 512;
#pragma unroll 1
        for (int kk = 0; kk < 128; kk += 8) {
          float4 wa[8], wb[8];
#pragma unroll
          for (int j = 0; j < 8; j++) {
            wa[j] = *(const float4*)(wqp + (size_t)(kk + j) * 512 + ua);
            wb[j] = *(const float4*)(wqp + (size_t)(kk + j) * 512 + ub);
          }
#pragma unroll
          for (int j = 0; j < 8; j++) {
            float h = sh_h1v[wave * 128 + kk + j];
            qa.x = fmaf(h, wa[j].x, qa.x); qa.y = fmaf(h, wa[j].y, qa.y);
            qa.z = fmaf(h, wa[j].z, qa.z); qa.w = fmaf(h, wa[j].w, qa.w);
            qb4.x = fmaf(h, wb[j].x, qb4.x); qb4.y = fmaf(h, wb[j].y, qb4.y);
            qb4.z = fmaf(h, wb[j].z, qb4.z); qb4.w = fmaf(h, wb[j].w, qb4.w);
          }
        }
        *(float4*)(redq + wave * 512 + ua) = qa;
        *(float4*)(redq + wave * 512 + ub) = qb4;
      }
      __syncthreads();
      for (int u = tid; u < 512; u += NTHR)
        sh_qb[u] = redq[u] + redq[512 + u] + redq[1024 + u] + redq[1536 + u] + battn[u];
      __syncthreads();
      // scores for this sub's 16 rows (|s|<=1 -> max-free exp)
      {
        float4 kv[4][2];
#pragma unroll
        for (int j = 0; j < 4; j++) {
          const float* kp = keysp + ((size_t)b * 128 + sub * 16 + wave * 4 + j) * 512;
          kv[j][0] = *(const float4*)(kp + lane * 4);
          kv[j][1] = *(const float4*)(kp + lane * 4 + 256);
        }
#pragma unroll
        for (int j = 0; j < 4; j++) {
          int tq = sub * 16 + wave * 4 + j;
          float s = 0.f;
#pragma unroll
          for (int hh = 0; hh < 2; hh++) {
            int u = lane * 4 + hh * 256;
            float4 k4 = kv[j][hh];
            s += sh_vnv[u + 0] * tanhft(k4.x + sh_qb[u + 0]);
            s += sh_vnv[u + 1] * tanhft(k4.y + sh_qb[u + 1]);
            s += sh_vnv[u + 2] * tanhft(k4.z + sh_qb[u + 2]);
            s += sh_vnv[u + 3] * tanhft(k4.w + sh_qb[u + 3]);
          }
#pragma unroll
          for (int off = 32; off > 0; off >>= 1) s += __shfl_xor(s, off, 64);
          if (lane == 0) sh_e[wave * 4 + j] = (tq < len) ? __expf(s) : 0.f;
        }
      }
      __syncthreads();
      if (tid == 0) {
        float es = 0.f;
#pragma unroll
        for (int i = 0; i < 16; i++) es += sh_e[i];
        atomicAdd(es_w + b, es);
      }
      // eattn += e-weighted eoutWal rows (cached reads, sealed)
      {
        int u2 = tid * 2;
        const float* wp2 = eoWal + ((size_t)b * 128 + sub * 16) * 512 + u2;
        float r0[16], r1[16];
#pragma unroll
        for (int j = 0; j < 16; j++) {
          r0[j] = wp2[(size_t)j * 512];
          r1[j] = wp2[(size_t)j * 512 + 1];
        }
        float a0 = 0.f, a1 = 0.f;
#pragma unroll
        for (int j = 0; j < 16; j++) {
          a0 = fmaf(sh_e[j], r0[j], a0);
          a1 = fmaf(sh_e[j], r1[j], a1);
        }
        atomicAdd(ea_w + b * 512 + u2, a0);
        atomicAdd(ea_w + b * 512 + u2 + 1, a1);
      }
      // h1w[b][sub*64..+64] = h1 @ Wal[0:512] (this sub's 64 cols)
      {
        int col = tid & 63, kq = tid >> 6;
        const float* wp2 = Wal + (size_t)(kq * 128) * 512 + sub * 64 + col;
        float pacc = 0.f;
#pragma unroll 1
        for (int k0 = 0; k0 < 128; k0 += 32) {
          float wv[32];
#pragma unroll
          for (int j = 0; j < 32; j++) wv[j] = wp2[(size_t)(k0 + j) * 512];
#pragma unroll
          for (int j = 0; j < 32; j++)
            pacc = fmaf(sh_h1v[kq * 128 + k0 + j], wv[j], pacc);
        }
        sh_hw[tid] = pacc;
        __syncthreads();
        if (tid < 64) {
          float s = sh_hw[tid] + sh_hw[64 + tid] + sh_hw[128 + tid] + sh_hw[192 + tid];
          cstore(h1w_w + b * 512 + sub * 64 + tid, s);
        }
      }
    }
    BAR();
  }

  // trailing: aall[127] from parity slot 1
  if (bid >= 384 && bid < 392) {
    const float* h1w_p = h1w + (size_t)1 * 16384;
    const float* ea_p  = eattn + (size_t)1 * 16384;
    const float* es_p  = esum + (size_t)1 * 512;
    int j = (bid - 384) * 256 + tid;
    int m = j >> 6, u0 = (j & 63) * 8;
    float v[8];
#pragma unroll
    for (int k = 0; k < 8; k++) v[k] = attn_of(h1w_p, ea_p, es_p, m, u0 + k);
#pragma unroll
    for (int k = 0; k < 8; k++) aall[(size_t)127 * 16384 + m * 512 + u0 + k] = v[k];
  }
  BARSEAL();  // seal aall; all out-scratch now dead

  // ---------------- batched projection: out = aall @ Wproj + bproj ----------------
#pragma unroll 1
  for (int task = bid; task < 564; task += NBLKS) {
    int nb = task >> 2, tq = task & 3;
    int n0 = nb * 64;
    const int col = n0 + lane;
    const bool ok = col < 9000;
#pragma unroll 1
    for (int t = tq * 32; t < tq * 32 + 32; t++) {
      const float* asrc = aall + (size_t)t * 16384;
      float acc[32];
#pragma unroll
      for (int m = 0; m < 32; m++) acc[m] = 0.f;
#pragma unroll 1
      for (int c = 0; c < 4; c++) {
        stage<128>(at, [&](int m, int kl) -> float {
          return asrc[(size_t)m * 512 + c * 128 + kl];
        });
        gemm_frag<128>(Wproj, 9000, col, ok, c * 128, at, acc);
      }
      red_write(red, acc);
      for (int i = tid; i < 2048; i += NTHR) {
        int m = i >> 6, nn = i & 63;
        int nc = n0 + nn;
        if (nc < 9000)
          out[((size_t)m * 128 + t) * 9000 + nc] = redsum(red, m, nn) + bproj[nc];
      }
    }
  }
#undef BAR
#undef BARSEAL
}

extern "C" void kernel_launch(void* const* d_in, const int* in_sizes, int n_in,
                              void* d_out, int out_size, void* d_ws, size_t ws_size,
                              hipStream_t stream) {
  (void)in_sizes; (void)n_in; (void)out_size; (void)ws_size;
  hipMemsetAsync(d_ws, 0, cfg::MEMSET_BYTES, stream);  // cells + all states
  hipLaunchKernelGGL(seq2seq_kernel, dim3(NBLKS), dim3(NTHR), 0, stream,
                     (const float*)d_in[0],   // embed_in
                     (const float*)d_in[1],   // dec_embed
                     (const int*)d_in[2],     // in_seq_len
                     (const float*)d_in[3],   // enc_fw_kernel
                     (const float*)d_in[4],   // enc_fw_bias
                     (const float*)d_in[5],   // enc_bw_kernel
                     (const float*)d_in[6],   // enc_bw_bias
                     (const float*)d_in[7],   // dec_kernel0
                     (const float*)d_in[8],   // dec_bias0
                     (const float*)d_in[9],   // dec_kernel1
                     (const float*)d_in[10],  // dec_bias1
                     (const float*)d_in[11],  // w_mem
                     (const float*)d_in[12],  // w_query
                     (const float*)d_in[13],  // b_attn
                     (const float*)d_in[14],  // v_attn
                     (const float*)d_in[15],  // g_attn
                     (const float*)d_in[16],  // w_attn_layer
                     (const float*)d_in[17],  // w_proj
                     (const float*)d_in[18],  // b_proj
                     (float*)d_out, (float*)d_ws);
}